// Round 20
// baseline (179.787 us; speedup 1.0000x reference)
//
#include <hip/hip_runtime.h>
#include <hip/hip_bf16.h>
#include <cstdint>
#include <cstddef>

#define Bq 4
#define Sq 2048
#define Dq 1024
#define Hq 16
#define HSq 64
#define Kc 1024

typedef short short8 __attribute__((ext_vector_type(8)));
typedef float f32x4 __attribute__((ext_vector_type(4)));

__device__ __forceinline__ unsigned short f2bf(float f){
  __hip_bfloat16 h = __float2bfloat16(f);
  return __builtin_bit_cast(unsigned short, h);
}

__device__ __forceinline__ float exp2hw(float x){
  float r;
  asm("v_exp_f32 %0, %1" : "=v"(r) : "v"(x));
  return r;
}
__device__ __forceinline__ unsigned cvtpk(float lo, float hi){
  unsigned r;
  asm("v_cvt_pk_bf16_f32 %0, %1, %2" : "=v"(r) : "v"(lo), "v"(hi));
  return r;
}
__device__ __forceinline__ float rcphw(float x){
  float r;
  asm("v_rcp_f32 %0, %1" : "=v"(r) : "v"(x));
  return r;
}

__device__ __forceinline__ void gl_lds16(const void* g, void* l){
  __builtin_amdgcn_global_load_lds((const __attribute__((address_space(1))) void*)(g),
                                   (__attribute__((address_space(3))) void*)(l), 16, 0, 0);
}

// ---------------- fused prep: 3x LayerNorm + 3x W-transpose + Wp cast ------------
__global__ __launch_bounds__(256) void prep_kernel(
    const float* __restrict__ v, const float* __restrict__ k, const float* __restrict__ q,
    const float* __restrict__ g, const float* __restrict__ bta,
    const float* __restrict__ Wq, const float* __restrict__ Wk, const float* __restrict__ Wv,
    const float* __restrict__ Wp,
    short* __restrict__ vo, short* __restrict__ ko, short* __restrict__ qo,
    short* __restrict__ wqt, short* __restrict__ wkt, short* __restrict__ wvt,
    short* __restrict__ wpb)
{
  const int bid = blockIdx.x;
  const int t = threadIdx.x;

  if (bid < 24576){
    const int which = bid >> 13;
    const int row   = bid & 8191;
    const float* x = (which==0) ? v : (which==1) ? k : q;
    short* out     = (which==0) ? vo : (which==1) ? ko : qo;
    const float* xr = x + (size_t)row * Dq;
    float4 vv = reinterpret_cast<const float4*>(xr)[t];
    float s  = vv.x + vv.y + vv.z + vv.w;
    float ss = vv.x*vv.x + vv.y*vv.y + vv.z*vv.z + vv.w*vv.w;
    #pragma unroll
    for (int o = 32; o >= 1; o >>= 1){ s += __shfl_xor(s, o); ss += __shfl_xor(ss, o); }
    __shared__ float red[8];
    const int wid = t >> 6;
    if ((t & 63) == 0){ red[wid] = s; red[4+wid] = ss; }
    __syncthreads();
    s  = red[0]+red[1]+red[2]+red[3];
    ss = red[4]+red[5]+red[6]+red[7];
    const float mu   = s * (1.0f/Dq);
    const float var  = ss * (1.0f/Dq) - mu*mu;
    const float rstd = rsqrtf(var + 1e-5f);
    float4 gv = reinterpret_cast<const float4*>(g)[t];
    float4 bv = reinterpret_cast<const float4*>(bta)[t];
    ushort4 o4;
    o4.x = f2bf((vv.x-mu)*rstd*gv.x + bv.x);
    o4.y = f2bf((vv.y-mu)*rstd*gv.y + bv.y);
    o4.z = f2bf((vv.z-mu)*rstd*gv.z + bv.z);
    o4.w = f2bf((vv.w-mu)*rstd*gv.w + bv.w);
    reinterpret_cast<ushort4*>(out + (size_t)row*Dq)[t] = o4;
  } else if (bid < 25344){
    const int idx = bid - 24576;
    const int z   = idx >> 8;
    const int rem = idx & 255;
    const int h   = rem >> 4;
    const int kt  = rem & 15;
    const float* Wsrc = (z==0) ? Wq : (z==1) ? Wk : Wv;
    short* Wdst       = (z==0) ? wqt : (z==1) ? wkt : wvt;
    const float scl   = (z==0) ? (0.03125f * 1.44269504f) : 1.0f;
    __shared__ short tb[64][68];
    const float* src = Wsrc + ((size_t)h*Kc + (size_t)kt*64) * HSq;
    #pragma unroll
    for (int c=0;c<4;c++){
      int lin = c*256 + t;
      int kr = lin >> 4;
      int e4 = (lin & 15) * 4;
      float4 vv = *reinterpret_cast<const float4*>(&src[(size_t)kr*HSq + e4]);
      tb[e4+0][kr] = (short)f2bf(vv.x*scl);
      tb[e4+1][kr] = (short)f2bf(vv.y*scl);
      tb[e4+2][kr] = (short)f2bf(vv.z*scl);
      tb[e4+3][kr] = (short)f2bf(vv.w*scl);
    }
    __syncthreads();
    short* dst = Wdst + (size_t)h*HSq*Kc + (size_t)kt*64;
    #pragma unroll
    for (int c=0;c<4;c++){
      int lin = c*256 + t;
      int er = lin >> 4;
      int k4 = (lin & 15) * 4;
      ushort4 o;
      o.x = (unsigned short)tb[er][k4+0];
      o.y = (unsigned short)tb[er][k4+1];
      o.z = (unsigned short)tb[er][k4+2];
      o.w = (unsigned short)tb[er][k4+3];
      *reinterpret_cast<ushort4*>(&dst[(size_t)er*Kc + k4]) = o;
    }
  } else {
    int i = (bid - 25344)*256 + t;
    float4 vv = reinterpret_cast<const float4*>(Wp)[i];
    ushort4 o; o.x=f2bf(vv.x); o.y=f2bf(vv.y); o.z=f2bf(vv.z); o.w=f2bf(vv.w);
    reinterpret_cast<ushort4*>(wpb)[i] = o;
  }
}

// ---------------- fused Q/K/V projection: 256x256 8-phase, 16 waves --------------
// (R17/R18-verified: ~70 us steady state, best of 7 structural variants)
__global__ __launch_bounds__(1024, 4) void proj3_kernel(
    const short* __restrict__ qn, const short* __restrict__ kn, const short* __restrict__ vn,
    const short* __restrict__ wqt, const short* __restrict__ wkt, const short* __restrict__ wvt,
    short* __restrict__ qh, short* __restrict__ kh, short* __restrict__ vhT)
{
  const int z = blockIdx.y;
  const short* A  = (z==0) ? qn  : (z==1) ? kn  : vn;
  const short* BT = (z==0) ? wqt : (z==1) ? wkt : wvt;

  const int i = blockIdx.x;
  const int bm = i & 31, bn = i >> 5;
  const int m0 = bm * 256;
  const int n0c = bn * 256;
  const int tid = threadIdx.x;
  const int lane = tid & 63, w = tid >> 6;   // 16 waves
  const int wm = w >> 2, wn = w & 3;         // 4M x 4N
  const int fr = lane & 15, fg = lane >> 4;

  __shared__ short As[2*256*64];
  __shared__ short Bs[2*256*64];

  f32x4 acc[4][4] = {};
  short8 bf[4][2];

  const int srow = tid >> 3;                       // 0..127
  const int sw   = ((tid & 7) << 4) ^ ((srow & 7) << 4);
  const char* aB = (const char*)(A  + (size_t)(m0  + srow)*Kc) + sw;
  const char* bB = (const char*)(BT + (size_t)(n0c + srow)*Kc) + sw;

#define STAGE(t, hh, buf) do{                                              \
    const bool isB_ = (hh) < 2;                                            \
    const char* s_ = (isB_ ? bB : aB) + (size_t)((hh)&1)*(128*2048) + (size_t)(t)*128; \
    char* d_ = (char*)(isB_ ? (void*)Bs : (void*)As) + (buf)*32768 + ((hh)&1)*16384 + w*1024; \
    gl_lds16(s_, d_);                                                      \
  }while(0)

#define READ_A(p, buf, af) do{                                             \
    const int r_ = (p)*64 + wm*16 + fr;                                    \
    _Pragma("unroll") for (int kk=0; kk<2; ++kk){                          \
      const int byt_ = (buf)*32768 + r_*128 + (((kk*4+fg)^(r_&7))<<4);     \
      af[kk] = *reinterpret_cast<const short8*>((const char*)As + byt_);   \
    }}while(0)

#define MFMA_P(p, af) do{                                                  \
    __builtin_amdgcn_s_setprio(1);                                         \
    _Pragma("unroll") for (int kk=0; kk<2; ++kk)                           \
      _Pragma("unroll") for (int nr=0; nr<4; ++nr)                         \
        acc[(p)][nr] = __builtin_amdgcn_mfma_f32_16x16x32_bf16(af[kk], bf[nr][kk], acc[(p)][nr], 0, 0, 0); \
    __builtin_amdgcn_s_setprio(0);                                         \
  }while(0)

#define DO_TILE(t, buf, HN) do{                                            \
    asm volatile("s_waitcnt vmcnt(1)" ::: "memory");                       \
    __builtin_amdgcn_s_barrier();                                          \
    _Pragma("unroll") for (int nr=0; nr<4; ++nr){                          \
      const int r_ = wn*64 + nr*16 + fr;                                   \
      _Pragma("unroll") for (int kk=0; kk<2; ++kk){                        \
        const int byt_ = (buf)*32768 + r_*128 + (((kk*4+fg)^(r_&7))<<4);   \
        bf[nr][kk] = *reinterpret_cast<const short8*>((const char*)Bs + byt_); \
      }}                                                                   \
    { short8 af[2]; READ_A(0, buf, af);                                    \
      if (HN) STAGE((t)+1, 0, (buf)^1);                                    \
      MFMA_P(0, af); }                                                     \
    { short8 af[2]; READ_A(1, buf, af);                                    \
      if (HN) STAGE((t)+1, 1, (buf)^1);                                    \
      MFMA_P(1, af); }                                                     \
    if (HN) { asm volatile("s_waitcnt vmcnt(2)" ::: "memory"); }           \
    else    { asm volatile("s_waitcnt vmcnt(0)" ::: "memory"); }           \
    __builtin_amdgcn_s_barrier();                                          \
    { short8 af[2]; READ_A(2, buf, af);                                    \
      if (HN) STAGE((t)+1, 2, (buf)^1);                                    \
      MFMA_P(2, af); }                                                     \
    { short8 af[2]; READ_A(3, buf, af);                                    \
      if (HN) STAGE((t)+1, 3, (buf)^1);                                    \
      MFMA_P(3, af); }                                                     \
  }while(0)

  STAGE(0, 0, 0); STAGE(0, 1, 0); STAGE(0, 2, 0); STAGE(0, 3, 0);

  for (int t2 = 0; t2 < 7; ++t2){
    const int t = t2*2;
    DO_TILE(t,   0, true);
    DO_TILE(t+1, 1, true);
  }
  DO_TILE(14, 0, true);
  DO_TILE(15, 1, false);

#undef DO_TILE
#undef MFMA_P
#undef READ_A
#undef STAGE

  if (z == 2){
    #pragma unroll
    for (int p=0; p<4; ++p){
      #pragma unroll
      for (int nr=0; nr<4; ++nr){
        int col = n0c + wn*64 + nr*16 + fr;
        int h = col >> 6, e = col & 63;
        int R = m0 + p*64 + wm*16 + fg*4;
        int bb = R >> 11, sPos = R & (Sq-1);
        uint2 o;
        o.x = cvtpk(acc[p][nr][0], acc[p][nr][1]);
        o.y = cvtpk(acc[p][nr][2], acc[p][nr][3]);
        *reinterpret_cast<uint2*>(&vhT[(((size_t)bb*Hq + h)*HSq + e)*Sq + sPos]) = o;
      }
    }
  } else {
    short* outb = z ? kh : qh;
    #pragma unroll
    for (int p=0; p<4; ++p){
      #pragma unroll
      for (int nr=0; nr<4; ++nr){
        int col = n0c + wn*64 + nr*16 + fr;
        int h = col >> 6, e = col & 63;
        #pragma unroll
        for (int r=0; r<4; ++r){
          int R = m0 + p*64 + wm*16 + fg*4 + r;
          int bb = R >> 11, sPos = R & (Sq-1);
          outb[(((size_t)bb*Hq + h)*Sq + sPos)*HSq + e] = (short)f2bf(acc[p][nr][r]);
        }
      }
    }
  }
}

// ---------------- output projection GEMM (fp32 out + bias), swapped epilogue -----
// mfma(B,A) -> D^T: lane fr = row (fixed), fg*4+r = 4 consecutive cols ->
// 16 coalesced float4 stores instead of 64 scalar dwords. (Epilogue math
// identical to R9's passing gemmo.)
__global__ __launch_bounds__(256) void gemmo_kernel(
    const short* __restrict__ A,
    const short* __restrict__ BT,
    const float* __restrict__ bias,
    float* __restrict__ outf)
{
  const int bid = blockIdx.x;
  const int c8_ = bid & 7, j = bid >> 3;
  const int bm = c8_*8 + (j & 7), bn = j >> 3;
  const int m0 = bm * 128;
  const int n0c = bn * 128;
  const int tid = threadIdx.x;
  const int lane = tid & 63, w = tid >> 6;
  const int wm = w >> 1, wn = w & 1;
  const int fr = lane & 15, fg = lane >> 4;

  __shared__ short As[128*64];
  __shared__ short Bs[128*64];

  f32x4 acc[4][4] = {};

  const int rowT = tid >> 3;
  const int inb  = (tid & 7) * 16;

  for (int kt = 0; kt < Kc/64; ++kt){
    const int k0 = kt*64;
    #pragma unroll
    for (int c=0;c<4;c++){
      int row = c*32 + rowT;
      int src = inb ^ ((row & 7) << 4);
      gl_lds16((const char*)(A  + (size_t)(m0  + row)*Kc + k0) + src,
               (char*)As + c*4096 + w*1024);
      gl_lds16((const char*)(BT + (size_t)(n0c + row)*Kc + k0) + src,
               (char*)Bs + c*4096 + w*1024);
    }
    __syncthreads();
    #pragma unroll
    for (int kk=0;kk<2;kk++){
      short8 af[4], bf8[4];
      #pragma unroll
      for (int mr=0;mr<4;mr++){
        int row = wm*64 + mr*16 + fr;
        int byt = row*128 + ((kk*64 + fg*16) ^ ((row & 7) << 4));
        af[mr] = *reinterpret_cast<const short8*>((const char*)As + byt);
      }
      #pragma unroll
      for (int nr=0;nr<4;nr++){
        int row = wn*64 + nr*16 + fr;
        int byt = row*128 + ((kk*64 + fg*16) ^ ((row & 7) << 4));
        bf8[nr] = *reinterpret_cast<const short8*>((const char*)Bs + byt);
      }
      #pragma unroll
      for (int mr=0;mr<4;mr++)
        #pragma unroll
        for (int nr=0;nr<4;nr++)
          acc[mr][nr] = __builtin_amdgcn_mfma_f32_16x16x32_bf16(bf8[nr], af[mr], acc[mr][nr], 0, 0, 0);
    }
    __syncthreads();
  }

  // D^T fragment: row R = ...+fr fixed, col = ...+fg*4+r consecutive -> float4
  float4 bv[4];
  #pragma unroll
  for (int nr=0;nr<4;nr++)
    bv[nr] = *reinterpret_cast<const float4*>(&bias[n0c + wn*64 + nr*16 + fg*4]);
  #pragma unroll
  for (int mr=0;mr<4;mr++){
    const int R = m0 + wm*64 + mr*16 + fr;
    #pragma unroll
    for (int nr=0;nr<4;nr++){
      int colb = n0c + wn*64 + nr*16 + fg*4;
      float4 o;
      o.x = acc[mr][nr][0] + bv[nr].x;
      o.y = acc[mr][nr][1] + bv[nr].y;
      o.z = acc[mr][nr][2] + bv[nr].z;
      o.w = acc[mr][nr][3] + bv[nr].w;
      *reinterpret_cast<float4*>(&outf[(size_t)R*Dq + colb]) = o;
    }
  }
}

// ---------------- flash attention (causal), swapped-MFMA, pair-balanced ----------
__global__ __launch_bounds__(256, 4) void attn_kernel(
    const short* __restrict__ qh, const short* __restrict__ kh,
    const short* __restrict__ vhT, short* __restrict__ attO)
{
  const int bid = blockIdx.x;
  const int jp  = bid >> 6;           // 0..7
  const int g   = bid & 63;
  const int h = g & 15, b = g >> 4;
  const short* Q  = qh  + (((size_t)b*Hq + h)*Sq)*HSq;
  const short* K  = kh  + (((size_t)b*Hq + h)*Sq)*HSq;
  const short* VT = vhT + (((size_t)b*Hq + h)*HSq)*Sq;   // [e][s]
  const int tid = threadIdx.x, w = tid >> 6, lane = tid & 63;
  const int fr = lane & 15, fg = lane >> 4;

  __shared__ short KsB[2][64*64];
  __shared__ short VtB[2][64*64];
  __shared__ short Ps[4][32][76];

  const int sRow = tid >> 3;
  const int swz  = ((tid & 7) << 4) ^ ((sRow & 7) << 4);
  const char* pK = (const char*)K  + (size_t)sRow*128      + swz;
  const char* pV = (const char*)VT + (size_t)sRow*(Sq*2)   + swz;

  short8 ones;
  #pragma unroll
  for (int ii=0;ii<8;ii++) ones[ii] = (short)0x3F80;

  for (int pass = 0; pass < 2; ++pass){
    const int qt = pass ? jp : (15 - jp);
    const int qbase = qt * 128;
    const int nkv = 2*qt + 2;

    short8 qa[2][2];
    #pragma unroll
    for (int mr=0;mr<2;mr++){
      const int qrow = qbase + w*32 + mr*16 + fr;
      #pragma unroll
      for (int kk=0;kk<2;kk++)
        qa[mr][kk] = *reinterpret_cast<const short8*>(&Q[(size_t)qrow*HSq + kk*32 + 8*fg]);
    }

    f32x4 accO[2][4] = {};
    f32x4 accL[2] = {};

    #pragma unroll
    for (int c=0;c<2;c++){
      gl_lds16(pK + c*4096,   (char*)KsB[0] + c*4096 + w*1024);
      gl_lds16(pV + c*131072, (char*)VtB[0] + c*4096 + w*1024);
    }
    __syncthreads();

    for (int kt0 = 0; kt0 < nkv; kt0 += 2){
      #pragma unroll
      for (int u = 0; u < 2; ++u){
        const int kt = kt0 + u;
        const int buf = u;

        if (kt+1 < nkv){
          const char* nK = pK + (size_t)(kt+1)*8192;
          const char* nV = pV + (size_t)(kt+1)*128;
          #pragma unroll
          for (int c=0;c<2;c++){
            gl_lds16(nK + c*4096,   (char*)KsB[buf^1] + c*4096 + w*1024);
            gl_lds16(nV + c*131072, (char*)VtB[buf^1] + c*4096 + w*1024);
          }
        }

        f32x4 sfr[2][4] = {};
        __builtin_amdgcn_s_setprio(1);
        #pragma unroll
        for (int kk=0;kk<2;kk++){
          short8 kb[4];
          #pragma unroll
          for (int n0=0;n0<4;n0++){
            int row = n0*16 + fr;
            int byt = row*128 + ((((kk*4+fg) ^ (row & 7))) << 4);
            kb[n0] = *reinterpret_cast<const short8*>((const char*)KsB[buf] + byt);
          }
          #pragma unroll
          for (int mr=0;mr<2;mr++)
            #pragma unroll
            for (int n0=0;n0<4;n0++)
              sfr[mr][n0] = __builtin_amdgcn_mfma_f32_16x16x32_bf16(kb[n0], qa[mr][kk], sfr[mr][n0], 0, 0, 0);
        }
        __builtin_amdgcn_s_setprio(0);

        #pragma unroll
        for (int mr=0;mr<2;mr++){
          const int qr = qbase + w*32 + mr*16 + fr;
          const bool needmask = (kt*64 + 63) > (qbase + w*32 + mr*16);
          #pragma unroll
          for (int n0=0;n0<4;n0++){
            float p0 = exp2hw(sfr[mr][n0][0]);
            float p1 = exp2hw(sfr[mr][n0][1]);
            float p2 = exp2hw(sfr[mr][n0][2]);
            float p3 = exp2hw(sfr[mr][n0][3]);
            if (needmask){
              int kc = kt*64 + n0*16 + fg*4;
              if (kc+0 > qr) p0 = 0.0f;
              if (kc+1 > qr) p1 = 0.0f;
              if (kc+2 > qr) p2 = 0.0f;
              if (kc+3 > qr) p3 = 0.0f;
            }
            uint2 u2;
            u2.x = cvtpk(p0, p1);
            u2.y = cvtpk(p2, p3);
            *reinterpret_cast<uint2*>(&Ps[w][mr*16 + fr][n0*16 + fg*4]) = u2;
          }
        }

        __builtin_amdgcn_s_setprio(1);
        #pragma unroll
        for (int kk=0;kk<2;kk++){
          short8 pa[2], vb[4];
          #pragma unroll
          for (int mr=0;mr<2;mr++)
            pa[mr] = *reinterpret_cast<short8*>(&Ps[w][mr*16 + fr][kk*32 + 8*fg]);
          #pragma unroll
          for (int n0=0;n0<4;n0++){
            int row = n0*16 + fr;
            int byt = row*128 + ((((kk*4+fg) ^ (row & 7))) << 4);
            vb[n0] = *reinterpret_cast<const short8*>((const char*)VtB[buf] + byt);
          }
          #pragma unroll
          for (int mr=0;mr<2;mr++){
            #pragma unroll
            for (int n0=0;n0<4;n0++)
              accO[mr][n0] = __builtin_amdgcn_mfma_f32_16x16x32_bf16(vb[n0], pa[mr], accO[mr][n0], 0, 0, 0);
            accL[mr] = __builtin_amdgcn_mfma_f32_16x16x32_bf16(ones, pa[mr], accL[mr], 0, 0, 0);
          }
        }
        __builtin_amdgcn_s_setprio(0);

        __syncthreads();
      }
    }

    #pragma unroll
    for (int mr=0;mr<2;mr++){
      float inv = rcphw(accL[mr][0]);
      const int qr = qbase + w*32 + mr*16 + fr;
      short* orow = attO + ((size_t)b*Sq + qr)*Dq + h*HSq;
      #pragma unroll
      for (int n0=0;n0<4;n0++){
        uint2 u2;
        u2.x = cvtpk(accO[mr][n0][0] * inv, accO[mr][n0][1] * inv);
        u2.y = cvtpk(accO[mr][n0][2] * inv, accO[mr][n0][3] * inv);
        *reinterpret_cast<uint2*>(&orow[n0*16 + fg*4]) = u2;
      }
    }
  }
}

extern "C" void kernel_launch(void* const* d_in, const int* in_sizes, int n_in,
                              void* d_out, int out_size, void* d_ws, size_t ws_size,
                              hipStream_t stream){
  const float* v_in = (const float*)d_in[0];
  const float* k_in = (const float*)d_in[1];
  const float* q_in = (const float*)d_in[2];
  const float* ln_g = (const float*)d_in[4];
  const float* ln_b = (const float*)d_in[5];
  const float* Wq   = (const float*)d_in[6];
  const float* Wk   = (const float*)d_in[7];
  const float* Wv   = (const float*)d_in[8];
  const float* Wp   = (const float*)d_in[9];
  const float* bp   = (const float*)d_in[10];
  float* out = (float*)d_out;

  char* ws = (char*)d_ws;
  const size_t BSD  = (size_t)Bq*Sq*Dq;
  const size_t BSD2 = BSD * 2;
  short* vn  = (short*)(ws);
  short* kn  = (short*)(ws + BSD2);
  short* qn  = (short*)(ws + 2*BSD2);
  short* wqt = (short*)(ws + 3*BSD2);
  short* wkt = (short*)(ws + 3*BSD2 + 2097152);
  short* wvt = (short*)(ws + 3*BSD2 + 2*2097152);
  short* wpb = (short*)(ws + 3*BSD2 + 3*2097152);
  short* qh  = (short*)(ws + 3*BSD2 + 4*2097152);
  short* kh  = qh + BSD;
  short* vhT = kh + BSD;
  short* attO = vn;   // vn dead after v-projection

  prep_kernel<<<26368, 256, 0, stream>>>(v_in, k_in, q_in, ln_g, ln_b,
                                         Wq, Wk, Wv, Wp,
                                         vn, kn, qn, wqt, wkt, wvt, wpb);

  proj3_kernel<<<dim3(128, 3), 1024, 0, stream>>>(qn, kn, vn, wqt, wkt, wvt, qh, kh, vhT);

  attn_kernel<<<512, 256, 0, stream>>>(qh, kh, vhT, attO);

  gemmo_kernel<<<512, 256, 0, stream>>>(attO, wpb, bp, out);
}

// Round 21
// 176.391 us; speedup vs baseline: 1.0193x; 1.0193x over previous
//
#include <hip/hip_runtime.h>
#include <hip/hip_bf16.h>
#include <cstdint>
#include <cstddef>

#define Bq 4
#define Sq 2048
#define Dq 1024
#define Hq 16
#define HSq 64
#define Kc 1024

typedef short short8 __attribute__((ext_vector_type(8)));
typedef float f32x4 __attribute__((ext_vector_type(4)));

__device__ __forceinline__ unsigned short f2bf(float f){
  __hip_bfloat16 h = __float2bfloat16(f);
  return __builtin_bit_cast(unsigned short, h);
}

__device__ __forceinline__ float exp2hw(float x){
  float r;
  asm("v_exp_f32 %0, %1" : "=v"(r) : "v"(x));
  return r;
}
__device__ __forceinline__ unsigned cvtpk(float lo, float hi){
  unsigned r;
  asm("v_cvt_pk_bf16_f32 %0, %1, %2" : "=v"(r) : "v"(lo), "v"(hi));
  return r;
}
__device__ __forceinline__ float rcphw(float x){
  float r;
  asm("v_rcp_f32 %0, %1" : "=v"(r) : "v"(x));
  return r;
}

__device__ __forceinline__ void gl_lds16(const void* g, void* l){
  __builtin_amdgcn_global_load_lds((const __attribute__((address_space(1))) void*)(g),
                                   (__attribute__((address_space(3))) void*)(l), 16, 0, 0);
}

// ---------------- fused prep: 3x LayerNorm + 3x W-transpose + Wp cast ------------
// At HBM roofline (~167 MB @ 6.3 TB/s ~ 26 us).
__global__ __launch_bounds__(256) void prep_kernel(
    const float* __restrict__ v, const float* __restrict__ k, const float* __restrict__ q,
    const float* __restrict__ g, const float* __restrict__ bta,
    const float* __restrict__ Wq, const float* __restrict__ Wk, const float* __restrict__ Wv,
    const float* __restrict__ Wp,
    short* __restrict__ vo, short* __restrict__ ko, short* __restrict__ qo,
    short* __restrict__ wqt, short* __restrict__ wkt, short* __restrict__ wvt,
    short* __restrict__ wpb)
{
  const int bid = blockIdx.x;
  const int t = threadIdx.x;

  if (bid < 24576){
    const int which = bid >> 13;
    const int row   = bid & 8191;
    const float* x = (which==0) ? v : (which==1) ? k : q;
    short* out     = (which==0) ? vo : (which==1) ? ko : qo;
    const float* xr = x + (size_t)row * Dq;
    float4 vv = reinterpret_cast<const float4*>(xr)[t];
    float s  = vv.x + vv.y + vv.z + vv.w;
    float ss = vv.x*vv.x + vv.y*vv.y + vv.z*vv.z + vv.w*vv.w;
    #pragma unroll
    for (int o = 32; o >= 1; o >>= 1){ s += __shfl_xor(s, o); ss += __shfl_xor(ss, o); }
    __shared__ float red[8];
    const int wid = t >> 6;
    if ((t & 63) == 0){ red[wid] = s; red[4+wid] = ss; }
    __syncthreads();
    s  = red[0]+red[1]+red[2]+red[3];
    ss = red[4]+red[5]+red[6]+red[7];
    const float mu   = s * (1.0f/Dq);
    const float var  = ss * (1.0f/Dq) - mu*mu;
    const float rstd = rsqrtf(var + 1e-5f);
    float4 gv = reinterpret_cast<const float4*>(g)[t];
    float4 bv = reinterpret_cast<const float4*>(bta)[t];
    ushort4 o4;
    o4.x = f2bf((vv.x-mu)*rstd*gv.x + bv.x);
    o4.y = f2bf((vv.y-mu)*rstd*gv.y + bv.y);
    o4.z = f2bf((vv.z-mu)*rstd*gv.z + bv.z);
    o4.w = f2bf((vv.w-mu)*rstd*gv.w + bv.w);
    reinterpret_cast<ushort4*>(out + (size_t)row*Dq)[t] = o4;
  } else if (bid < 25344){
    const int idx = bid - 24576;
    const int z   = idx >> 8;
    const int rem = idx & 255;
    const int h   = rem >> 4;
    const int kt  = rem & 15;
    const float* Wsrc = (z==0) ? Wq : (z==1) ? Wk : Wv;
    short* Wdst       = (z==0) ? wqt : (z==1) ? wkt : wvt;
    const float scl   = (z==0) ? (0.03125f * 1.44269504f) : 1.0f;
    __shared__ short tb[64][68];
    const float* src = Wsrc + ((size_t)h*Kc + (size_t)kt*64) * HSq;
    #pragma unroll
    for (int c=0;c<4;c++){
      int lin = c*256 + t;
      int kr = lin >> 4;
      int e4 = (lin & 15) * 4;
      float4 vv = *reinterpret_cast<const float4*>(&src[(size_t)kr*HSq + e4]);
      tb[e4+0][kr] = (short)f2bf(vv.x*scl);
      tb[e4+1][kr] = (short)f2bf(vv.y*scl);
      tb[e4+2][kr] = (short)f2bf(vv.z*scl);
      tb[e4+3][kr] = (short)f2bf(vv.w*scl);
    }
    __syncthreads();
    short* dst = Wdst + (size_t)h*HSq*Kc + (size_t)kt*64;
    #pragma unroll
    for (int c=0;c<4;c++){
      int lin = c*256 + t;
      int er = lin >> 4;
      int k4 = (lin & 15) * 4;
      ushort4 o;
      o.x = (unsigned short)tb[er][k4+0];
      o.y = (unsigned short)tb[er][k4+1];
      o.z = (unsigned short)tb[er][k4+2];
      o.w = (unsigned short)tb[er][k4+3];
      *reinterpret_cast<ushort4*>(&dst[(size_t)er*Kc + k4]) = o;
    }
  } else {
    int i = (bid - 25344)*256 + t;
    float4 vv = reinterpret_cast<const float4*>(Wp)[i];
    ushort4 o; o.x=f2bf(vv.x); o.y=f2bf(vv.y); o.z=f2bf(vv.z); o.w=f2bf(vv.w);
    reinterpret_cast<ushort4*>(wpb)[i] = o;
  }
}

// ---------------- fused Q/K/V projection: 256x256 8-phase, 16 waves --------------
// Best of 8 structural variants tried (R7..R17): ~70 us steady state.
__global__ __launch_bounds__(1024, 4) void proj3_kernel(
    const short* __restrict__ qn, const short* __restrict__ kn, const short* __restrict__ vn,
    const short* __restrict__ wqt, const short* __restrict__ wkt, const short* __restrict__ wvt,
    short* __restrict__ qh, short* __restrict__ kh, short* __restrict__ vhT)
{
  const int z = blockIdx.y;
  const short* A  = (z==0) ? qn  : (z==1) ? kn  : vn;
  const short* BT = (z==0) ? wqt : (z==1) ? wkt : wvt;

  const int i = blockIdx.x;
  const int bm = i & 31, bn = i >> 5;
  const int m0 = bm * 256;
  const int n0c = bn * 256;
  const int tid = threadIdx.x;
  const int lane = tid & 63, w = tid >> 6;   // 16 waves
  const int wm = w >> 2, wn = w & 3;         // 4M x 4N
  const int fr = lane & 15, fg = lane >> 4;

  __shared__ short As[2*256*64];
  __shared__ short Bs[2*256*64];

  f32x4 acc[4][4] = {};
  short8 bf[4][2];

  const int srow = tid >> 3;                       // 0..127
  const int sw   = ((tid & 7) << 4) ^ ((srow & 7) << 4);
  const char* aB = (const char*)(A  + (size_t)(m0  + srow)*Kc) + sw;
  const char* bB = (const char*)(BT + (size_t)(n0c + srow)*Kc) + sw;

#define STAGE(t, hh, buf) do{                                              \
    const bool isB_ = (hh) < 2;                                            \
    const char* s_ = (isB_ ? bB : aB) + (size_t)((hh)&1)*(128*2048) + (size_t)(t)*128; \
    char* d_ = (char*)(isB_ ? (void*)Bs : (void*)As) + (buf)*32768 + ((hh)&1)*16384 + w*1024; \
    gl_lds16(s_, d_);                                                      \
  }while(0)

#define READ_A(p, buf, af) do{                                             \
    const int r_ = (p)*64 + wm*16 + fr;                                    \
    _Pragma("unroll") for (int kk=0; kk<2; ++kk){                          \
      const int byt_ = (buf)*32768 + r_*128 + (((kk*4+fg)^(r_&7))<<4);     \
      af[kk] = *reinterpret_cast<const short8*>((const char*)As + byt_);   \
    }}while(0)

#define MFMA_P(p, af) do{                                                  \
    __builtin_amdgcn_s_setprio(1);                                         \
    _Pragma("unroll") for (int kk=0; kk<2; ++kk)                           \
      _Pragma("unroll") for (int nr=0; nr<4; ++nr)                         \
        acc[(p)][nr] = __builtin_amdgcn_mfma_f32_16x16x32_bf16(af[kk], bf[nr][kk], acc[(p)][nr], 0, 0, 0); \
    __builtin_amdgcn_s_setprio(0);                                         \
  }while(0)

#define DO_TILE(t, buf, HN) do{                                            \
    asm volatile("s_waitcnt vmcnt(1)" ::: "memory");                       \
    __builtin_amdgcn_s_barrier();                                          \
    _Pragma("unroll") for (int nr=0; nr<4; ++nr){                          \
      const int r_ = wn*64 + nr*16 + fr;                                   \
      _Pragma("unroll") for (int kk=0; kk<2; ++kk){                        \
        const int byt_ = (buf)*32768 + r_*128 + (((kk*4+fg)^(r_&7))<<4);   \
        bf[nr][kk] = *reinterpret_cast<const short8*>((const char*)Bs + byt_); \
      }}                                                                   \
    { short8 af[2]; READ_A(0, buf, af);                                    \
      if (HN) STAGE((t)+1, 0, (buf)^1);                                    \
      MFMA_P(0, af); }                                                     \
    { short8 af[2]; READ_A(1, buf, af);                                    \
      if (HN) STAGE((t)+1, 1, (buf)^1);                                    \
      MFMA_P(1, af); }                                                     \
    if (HN) { asm volatile("s_waitcnt vmcnt(2)" ::: "memory"); }           \
    else    { asm volatile("s_waitcnt vmcnt(0)" ::: "memory"); }           \
    __builtin_amdgcn_s_barrier();                                          \
    { short8 af[2]; READ_A(2, buf, af);                                    \
      if (HN) STAGE((t)+1, 2, (buf)^1);                                    \
      MFMA_P(2, af); }                                                     \
    { short8 af[2]; READ_A(3, buf, af);                                    \
      if (HN) STAGE((t)+1, 3, (buf)^1);                                    \
      MFMA_P(3, af); }                                                     \
  }while(0)

  STAGE(0, 0, 0); STAGE(0, 1, 0); STAGE(0, 2, 0); STAGE(0, 3, 0);

  for (int t2 = 0; t2 < 7; ++t2){
    const int t = t2*2;
    DO_TILE(t,   0, true);
    DO_TILE(t+1, 1, true);
  }
  DO_TILE(14, 0, true);
  DO_TILE(15, 1, false);

#undef DO_TILE
#undef MFMA_P
#undef READ_A
#undef STAGE

  if (z == 2){
    #pragma unroll
    for (int p=0; p<4; ++p){
      #pragma unroll
      for (int nr=0; nr<4; ++nr){
        int col = n0c + wn*64 + nr*16 + fr;
        int h = col >> 6, e = col & 63;
        int R = m0 + p*64 + wm*16 + fg*4;
        int bb = R >> 11, sPos = R & (Sq-1);
        uint2 o;
        o.x = cvtpk(acc[p][nr][0], acc[p][nr][1]);
        o.y = cvtpk(acc[p][nr][2], acc[p][nr][3]);
        *reinterpret_cast<uint2*>(&vhT[(((size_t)bb*Hq + h)*HSq + e)*Sq + sPos]) = o;
      }
    }
  } else {
    short* outb = z ? kh : qh;
    #pragma unroll
    for (int p=0; p<4; ++p){
      #pragma unroll
      for (int nr=0; nr<4; ++nr){
        int col = n0c + wn*64 + nr*16 + fr;
        int h = col >> 6, e = col & 63;
        #pragma unroll
        for (int r=0; r<4; ++r){
          int R = m0 + p*64 + wm*16 + fg*4 + r;
          int bb = R >> 11, sPos = R & (Sq-1);
          outb[(((size_t)bb*Hq + h)*Sq + sPos)*HSq + e] = (short)f2bf(acc[p][nr][r]);
        }
      }
    }
  }
}

// ---------------- output projection GEMM (fp32 out + bias), 128x128 ----------------
// (R20's swapped-operand epilogue measured neutral-to-negative; reverted.)
__global__ __launch_bounds__(256) void gemmo_kernel(
    const short* __restrict__ A,
    const short* __restrict__ BT,
    const float* __restrict__ bias,
    float* __restrict__ outf)
{
  const int bid = blockIdx.x;
  const int c8_ = bid & 7, j = bid >> 3;
  const int bm = c8_*8 + (j & 7), bn = j >> 3;
  const int m0 = bm * 128;
  const int n0c = bn * 128;
  const int tid = threadIdx.x;
  const int lane = tid & 63, w = tid >> 6;
  const int wm = w >> 1, wn = w & 1;
  const int fr = lane & 15, fg = lane >> 4;

  __shared__ short As[128*64];
  __shared__ short Bs[128*64];

  f32x4 acc[4][4] = {};

  const int rowT = tid >> 3;
  const int inb  = (tid & 7) * 16;

  for (int kt = 0; kt < Kc/64; ++kt){
    const int k0 = kt*64;
    #pragma unroll
    for (int c=0;c<4;c++){
      int row = c*32 + rowT;
      int src = inb ^ ((row & 7) << 4);
      gl_lds16((const char*)(A  + (size_t)(m0  + row)*Kc + k0) + src,
               (char*)As + c*4096 + w*1024);
      gl_lds16((const char*)(BT + (size_t)(n0c + row)*Kc + k0) + src,
               (char*)Bs + c*4096 + w*1024);
    }
    __syncthreads();
    #pragma unroll
    for (int kk=0;kk<2;kk++){
      short8 af[4], bf8[4];
      #pragma unroll
      for (int mr=0;mr<4;mr++){
        int row = wm*64 + mr*16 + fr;
        int byt = row*128 + ((kk*64 + fg*16) ^ ((row & 7) << 4));
        af[mr] = *reinterpret_cast<const short8*>((const char*)As + byt);
      }
      #pragma unroll
      for (int nr=0;nr<4;nr++){
        int row = wn*64 + nr*16 + fr;
        int byt = row*128 + ((kk*64 + fg*16) ^ ((row & 7) << 4));
        bf8[nr] = *reinterpret_cast<const short8*>((const char*)Bs + byt);
      }
      #pragma unroll
      for (int mr=0;mr<4;mr++)
        #pragma unroll
        for (int nr=0;nr<4;nr++)
          acc[mr][nr] = __builtin_amdgcn_mfma_f32_16x16x32_bf16(af[mr], bf8[nr], acc[mr][nr], 0, 0, 0);
    }
    __syncthreads();
  }

  #pragma unroll
  for (int mr=0;mr<4;mr++){
    #pragma unroll
    for (int nr=0;nr<4;nr++){
      int col = n0c + wn*64 + nr*16 + fr;
      #pragma unroll
      for (int r=0;r<4;r++){
        int R = m0 + wm*64 + mr*16 + fg*4 + r;
        outf[(size_t)R*Dq + col] = acc[mr][nr][r] + bias[col];
      }
    }
  }
}

// ---------------- flash attention (causal), swapped-MFMA, pair-balanced ----------
__global__ __launch_bounds__(256, 4) void attn_kernel(
    const short* __restrict__ qh, const short* __restrict__ kh,
    const short* __restrict__ vhT, short* __restrict__ attO)
{
  const int bid = blockIdx.x;
  const int jp  = bid >> 6;           // 0..7
  const int g   = bid & 63;
  const int h = g & 15, b = g >> 4;
  const short* Q  = qh  + (((size_t)b*Hq + h)*Sq)*HSq;
  const short* K  = kh  + (((size_t)b*Hq + h)*Sq)*HSq;
  const short* VT = vhT + (((size_t)b*Hq + h)*HSq)*Sq;   // [e][s]
  const int tid = threadIdx.x, w = tid >> 6, lane = tid & 63;
  const int fr = lane & 15, fg = lane >> 4;

  __shared__ short KsB[2][64*64];
  __shared__ short VtB[2][64*64];
  __shared__ short Ps[4][32][76];

  const int sRow = tid >> 3;
  const int swz  = ((tid & 7) << 4) ^ ((sRow & 7) << 4);
  const char* pK = (const char*)K  + (size_t)sRow*128      + swz;
  const char* pV = (const char*)VT + (size_t)sRow*(Sq*2)   + swz;

  short8 ones;
  #pragma unroll
  for (int ii=0;ii<8;ii++) ones[ii] = (short)0x3F80;

  for (int pass = 0; pass < 2; ++pass){
    const int qt = pass ? jp : (15 - jp);
    const int qbase = qt * 128;
    const int nkv = 2*qt + 2;

    short8 qa[2][2];
    #pragma unroll
    for (int mr=0;mr<2;mr++){
      const int qrow = qbase + w*32 + mr*16 + fr;
      #pragma unroll
      for (int kk=0;kk<2;kk++)
        qa[mr][kk] = *reinterpret_cast<const short8*>(&Q[(size_t)qrow*HSq + kk*32 + 8*fg]);
    }

    f32x4 accO[2][4] = {};
    f32x4 accL[2] = {};

    #pragma unroll
    for (int c=0;c<2;c++){
      gl_lds16(pK + c*4096,   (char*)KsB[0] + c*4096 + w*1024);
      gl_lds16(pV + c*131072, (char*)VtB[0] + c*4096 + w*1024);
    }
    __syncthreads();

    for (int kt0 = 0; kt0 < nkv; kt0 += 2){
      #pragma unroll
      for (int u = 0; u < 2; ++u){
        const int kt = kt0 + u;
        const int buf = u;

        if (kt+1 < nkv){
          const char* nK = pK + (size_t)(kt+1)*8192;
          const char* nV = pV + (size_t)(kt+1)*128;
          #pragma unroll
          for (int c=0;c<2;c++){
            gl_lds16(nK + c*4096,   (char*)KsB[buf^1] + c*4096 + w*1024);
            gl_lds16(nV + c*131072, (char*)VtB[buf^1] + c*4096 + w*1024);
          }
        }

        f32x4 sfr[2][4] = {};
        __builtin_amdgcn_s_setprio(1);
        #pragma unroll
        for (int kk=0;kk<2;kk++){
          short8 kb[4];
          #pragma unroll
          for (int n0=0;n0<4;n0++){
            int row = n0*16 + fr;
            int byt = row*128 + ((((kk*4+fg) ^ (row & 7))) << 4);
            kb[n0] = *reinterpret_cast<const short8*>((const char*)KsB[buf] + byt);
          }
          #pragma unroll
          for (int mr=0;mr<2;mr++)
            #pragma unroll
            for (int n0=0;n0<4;n0++)
              sfr[mr][n0] = __builtin_amdgcn_mfma_f32_16x16x32_bf16(kb[n0], qa[mr][kk], sfr[mr][n0], 0, 0, 0);
        }
        __builtin_amdgcn_s_setprio(0);

        #pragma unroll
        for (int mr=0;mr<2;mr++){
          const int qr = qbase + w*32 + mr*16 + fr;
          const bool needmask = (kt*64 + 63) > (qbase + w*32 + mr*16);
          #pragma unroll
          for (int n0=0;n0<4;n0++){
            float p0 = exp2hw(sfr[mr][n0][0]);
            float p1 = exp2hw(sfr[mr][n0][1]);
            float p2 = exp2hw(sfr[mr][n0][2]);
            float p3 = exp2hw(sfr[mr][n0][3]);
            if (needmask){
              int kc = kt*64 + n0*16 + fg*4;
              if (kc+0 > qr) p0 = 0.0f;
              if (kc+1 > qr) p1 = 0.0f;
              if (kc+2 > qr) p2 = 0.0f;
              if (kc+3 > qr) p3 = 0.0f;
            }
            uint2 u2;
            u2.x = cvtpk(p0, p1);
            u2.y = cvtpk(p2, p3);
            *reinterpret_cast<uint2*>(&Ps[w][mr*16 + fr][n0*16 + fg*4]) = u2;
          }
        }

        __builtin_amdgcn_s_setprio(1);
        #pragma unroll
        for (int kk=0;kk<2;kk++){
          short8 pa[2], vb[4];
          #pragma unroll
          for (int mr=0;mr<2;mr++)
            pa[mr] = *reinterpret_cast<short8*>(&Ps[w][mr*16 + fr][kk*32 + 8*fg]);
          #pragma unroll
          for (int n0=0;n0<4;n0++){
            int row = n0*16 + fr;
            int byt = row*128 + ((((kk*4+fg) ^ (row & 7))) << 4);
            vb[n0] = *reinterpret_cast<const short8*>((const char*)VtB[buf] + byt);
          }
          #pragma unroll
          for (int mr=0;mr<2;mr++){
            #pragma unroll
            for (int n0=0;n0<4;n0++)
              accO[mr][n0] = __builtin_amdgcn_mfma_f32_16x16x32_bf16(vb[n0], pa[mr], accO[mr][n0], 0, 0, 0);
            accL[mr] = __builtin_amdgcn_mfma_f32_16x16x32_bf16(ones, pa[mr], accL[mr], 0, 0, 0);
          }
        }
        __builtin_amdgcn_s_setprio(0);

        __syncthreads();
      }
    }

    #pragma unroll
    for (int mr=0;mr<2;mr++){
      float inv = rcphw(accL[mr][0]);
      const int qr = qbase + w*32 + mr*16 + fr;
      short* orow = attO + ((size_t)b*Sq + qr)*Dq + h*HSq;
      #pragma unroll
      for (int n0=0;n0<4;n0++){
        uint2 u2;
        u2.x = cvtpk(accO[mr][n0][0] * inv, accO[mr][n0][1] * inv);
        u2.y = cvtpk(accO[mr][n0][2] * inv, accO[mr][n0][3] * inv);
        *reinterpret_cast<uint2*>(&orow[n0*16 + fg*4]) = u2;
      }
    }
  }
}

extern "C" void kernel_launch(void* const* d_in, const int* in_sizes, int n_in,
                              void* d_out, int out_size, void* d_ws, size_t ws_size,
                              hipStream_t stream){
  const float* v_in = (const float*)d_in[0];
  const float* k_in = (const float*)d_in[1];
  const float* q_in = (const float*)d_in[2];
  const float* ln_g = (const float*)d_in[4];
  const float* ln_b = (const float*)d_in[5];
  const float* Wq   = (const float*)d_in[6];
  const float* Wk   = (const float*)d_in[7];
  const float* Wv   = (const float*)d_in[8];
  const float* Wp   = (const float*)d_in[9];
  const float* bp   = (const float*)d_in[10];
  float* out = (float*)d_out;

  char* ws = (char*)d_ws;
  const size_t BSD  = (size_t)Bq*Sq*Dq;
  const size_t BSD2 = BSD * 2;
  short* vn  = (short*)(ws);
  short* kn  = (short*)(ws + BSD2);
  short* qn  = (short*)(ws + 2*BSD2);
  short* wqt = (short*)(ws + 3*BSD2);
  short* wkt = (short*)(ws + 3*BSD2 + 2097152);
  short* wvt = (short*)(ws + 3*BSD2 + 2*2097152);
  short* wpb = (short*)(ws + 3*BSD2 + 3*2097152);
  short* qh  = (short*)(ws + 3*BSD2 + 4*2097152);
  short* kh  = qh + BSD;
  short* vhT = kh + BSD;
  short* attO = vn;   // vn dead after v-projection

  prep_kernel<<<26368, 256, 0, stream>>>(v_in, k_in, q_in, ln_g, ln_b,
                                         Wq, Wk, Wv, Wp,
                                         vn, kn, qn, wqt, wkt, wvt, wpb);

  proj3_kernel<<<dim3(128, 3), 1024, 0, stream>>>(qn, kn, vn, wqt, wkt, wvt, qh, kh, vhT);

  attn_kernel<<<512, 256, 0, stream>>>(qh, kh, vhT, attO);

  gemmo_kernel<<<512, 256, 0, stream>>>(attO, wpb, bp, out);
}